// Round 6
// baseline (405.168 us; speedup 1.0000x reference)
//
#include <hip/hip_runtime.h>
#include <hip/hip_bf16.h>

#define ALPHA 0.2f
typedef unsigned int uint32;
typedef __attribute__((ext_vector_type(8))) short short8;   // 8 bf16 = 4 VGPRs
typedef __attribute__((ext_vector_type(4))) float f32x4;

static __device__ __forceinline__ unsigned short f2bf(float f) {
    unsigned int u = __float_as_uint(f);
    u += 0x7fffu + ((u >> 16) & 1u);          // RNE
    return (unsigned short)(u >> 16);
}
static __device__ __forceinline__ uint32 pk2bf(float lo, float hi) {
    return (uint32)f2bf(lo) | ((uint32)f2bf(hi) << 16);
}
static __device__ __forceinline__ float bflo(uint32 u) { return __uint_as_float(u << 16); }
static __device__ __forceinline__ float bfhi(uint32 u) { return __uint_as_float(u & 0xffff0000u); }

// ---------------------------------------------------------------------------
// K1 = hist (blocks 0..nbh-1) ∥ prep (blocks nbh..nbh+24).   [round-2 verbatim]
// hist: eslot[e] = counts[dst]++ (atomic-return over 800k independent threads;
//       round-3 proved moving this to scatter's cursor serializes: 108µs).
// prep: transpose-cast W -> WBT, Wout -> WoutT (bf16 [n][c]); w1f/w2f = W@a.
// ---------------------------------------------------------------------------
__global__ __launch_bounds__(256) void k1_hist_prep(const int* __restrict__ ei,
                                                    int* __restrict__ counts,
                                                    int* __restrict__ eslot, int E,
                                                    const float* __restrict__ W,
                                                    const float* __restrict__ Wout,
                                                    const float* __restrict__ a1,
                                                    const float* __restrict__ a2,
                                                    unsigned short* __restrict__ WBT,
                                                    unsigned short* __restrict__ WoutT,
                                                    float* __restrict__ w1f,
                                                    float* __restrict__ w2f, int nbh) {
    const int tid = threadIdx.x;
    if ((int)blockIdx.x < nbh) {
        int e = blockIdx.x * 256 + tid;
        if (e < E) eslot[e] = atomicAdd(&counts[ei[E + e]], 1);
        return;
    }
    int bp = blockIdx.x - nbh;
    if (bp < 8) {
        for (int n = bp * 16; n < bp * 16 + 16; ++n)
            for (int c = tid; c < 128; c += 256)
                WBT[n * 128 + c] = f2bf(W[c * 128 + n]);
    } else if (bp < 24) {
        int q = bp - 8;
        for (int n = q * 8; n < q * 8 + 8; ++n)
            for (int c = tid; c < 384; c += 256)
                WoutT[n * 384 + c] = f2bf(Wout[c * 128 + n]);
    } else {
        if (tid < 128) {
            float acc1 = 0.f, acc2 = 0.f;
            for (int c = 0; c < 128; ++c) {
                float w = W[tid * 128 + c];
                acc1 += w * a1[c];
                acc2 += w * a2[c];
            }
            w1f[tid] = acc1;
            w2f[tid] = acc2;
        }
    }
}

// ---------------------------------------------------------------------------
// K2 = mmy ∥ scan.   [round-2 verbatim]
// ---------------------------------------------------------------------------
__global__ __launch_bounds__(256) void k2_mmy_scan(const float* __restrict__ h,
                                                   const unsigned short* __restrict__ WBT,
                                                   const float* __restrict__ w1f,
                                                   const float* __restrict__ w2f,
                                                   unsigned short* __restrict__ Whb,
                                                   float* __restrict__ s1,
                                                   uint2* __restrict__ PR, int M,
                                                   const int* __restrict__ counts,
                                                   int* __restrict__ rowptr,
                                                   int N, int E, int nbm) {
    __shared__ unsigned short As[64 * 128];   // 16KB
    __shared__ unsigned short Bs[128 * 128];  // 32KB (also epilogue transpose buf)
    __shared__ float ws1[128], ws2[128];
    __shared__ int wsums[4];
    __shared__ int base_s;
    const int tid = threadIdx.x;

    if ((int)blockIdx.x >= nbm) {
        // ---------------- scan ----------------
        const int bs   = blockIdx.x - nbm;
        const int lane = tid & 63, wv = tid >> 6;
        const int limit = bs * 1024;
        int acc = 0;
        for (int i = tid * 4; i < limit; i += 1024) {
            int4 v = *(const int4*)(counts + i);
            acc += v.x + v.y + v.z + v.w;
        }
#pragma unroll
        for (int off = 32; off > 0; off >>= 1) acc += __shfl_down(acc, off);
        if (lane == 0) wsums[wv] = acc;
        __syncthreads();
        if (tid == 0) base_s = wsums[0] + wsums[1] + wsums[2] + wsums[3];
        __syncthreads();
        int i0 = bs * 1024 + tid * 4;
        int v0 = 0, v1 = 0, v2 = 0, v3 = 0;
        if (i0 + 3 < N) {
            int4 v = *(const int4*)(counts + i0);
            v0 = v.x; v1 = v.y; v2 = v.z; v3 = v.w;
        } else {
            if (i0 + 0 < N) v0 = counts[i0 + 0];
            if (i0 + 1 < N) v1 = counts[i0 + 1];
            if (i0 + 2 < N) v2 = counts[i0 + 2];
            if (i0 + 3 < N) v3 = counts[i0 + 3];
        }
        int tt = v0 + v1 + v2 + v3;
        int incl = tt;
#pragma unroll
        for (int off = 1; off < 64; off <<= 1) {
            int t = __shfl_up(incl, off);
            if (lane >= off) incl += t;
        }
        __syncthreads();
        if (lane == 63) wsums[wv] = incl;
        __syncthreads();
        int woff = 0;
        for (int w2 = 0; w2 < wv; ++w2) woff += wsums[w2];
        int base = base_s + woff + (incl - tt);
        if (i0 + 0 < N) { rowptr[i0 + 0] = base;                PR[i0 + 0].y = (uint32)base; }
        if (i0 + 1 < N) { rowptr[i0 + 1] = base + v0;           PR[i0 + 1].y = (uint32)(base + v0); }
        if (i0 + 2 < N) { rowptr[i0 + 2] = base + v0 + v1;      PR[i0 + 2].y = (uint32)(base + v0 + v1); }
        if (i0 + 3 < N) { rowptr[i0 + 3] = base + v0 + v1 + v2; PR[i0 + 3].y = (uint32)(base + v0 + v1 + v2); }
        if (bs == 0 && tid == 0) rowptr[N] = E;
        return;
    }

    // ---------------- mmy (64-row tile) ----------------
    const int lane = tid & 63;
    const int w    = tid >> 6;
    const int row0 = blockIdx.x * 64;

    if (tid < 128) ws1[tid] = w1f[tid];
    else           ws2[tid - 128] = w2f[tid - 128];
    __syncthreads();

    const float4* h4 = (const float4*)h;
    float sp1[4], sp2[4];
#pragma unroll
    for (int m = 0; m < 4; ++m) { sp1[m] = 0.f; sp2[m] = 0.f; }
#pragma unroll
    for (int m = 0; m < 4; ++m) {
        int i = m * 256 + tid;            // 0..1023
        int r = i >> 4, g = i & 15;
        int rg = row0 + r;
        float4 va = make_float4(0.f, 0.f, 0.f, 0.f), vb = va;
        if (rg < M) {
            va = h4[(size_t)rg * 32 + g * 2];
            vb = h4[(size_t)rg * 32 + g * 2 + 1];
        }
        float4 wa1 = *(const float4*)(ws1 + g * 8);
        float4 wb1 = *(const float4*)(ws1 + g * 8 + 4);
        float4 wa2 = *(const float4*)(ws2 + g * 8);
        float4 wb2 = *(const float4*)(ws2 + g * 8 + 4);
        sp1[m] += va.x * wa1.x + va.y * wa1.y + va.z * wa1.z + va.w * wa1.w
                + vb.x * wb1.x + vb.y * wb1.y + vb.z * wb1.z + vb.w * wb1.w;
        sp2[m] += va.x * wa2.x + va.y * wa2.y + va.z * wa2.z + va.w * wa2.w
                + vb.x * wb2.x + vb.y * wb2.y + vb.z * wb2.z + vb.w * wb2.w;
        uint4 u;
        u.x = pk2bf(va.x, va.y); u.y = pk2bf(va.z, va.w);
        u.z = pk2bf(vb.x, vb.y); u.w = pk2bf(vb.z, vb.w);
        *(uint4*)(As + r * 128 + ((g ^ (r & 15)) * 8)) = u;
    }
#pragma unroll
    for (int m = 0; m < 4; ++m) {
#pragma unroll
        for (int off = 1; off < 16; off <<= 1) {
            sp1[m] += __shfl_xor(sp1[m], off);
            sp2[m] += __shfl_xor(sp2[m], off);
        }
    }
    if ((tid & 15) == 0) {
#pragma unroll
        for (int m = 0; m < 4; ++m) {
            int rg = row0 + m * 16 + (tid >> 4);
            if (rg < M) { s1[rg] = sp1[m]; PR[rg].x = __float_as_uint(sp2[m]); }
        }
    }

#pragma unroll
    for (int m = 0; m < 8; ++m) {
        int i = m * 256 + tid;
        int n = i >> 4, g = i & 15;
        uint4 v = *(const uint4*)(WBT + n * 128 + g * 8);
        *(uint4*)(Bs + n * 128 + ((g ^ (n & 15)) * 8)) = v;
    }
    __syncthreads();

    const int ml   = lane & 15;
    const int quad = lane >> 4;
    f32x4 acc[8];
#pragma unroll
    for (int nt = 0; nt < 8; ++nt) acc[nt] = (f32x4){0.f, 0.f, 0.f, 0.f};
#pragma unroll
    for (int kc = 0; kc < 4; ++kc) {
        int gl = ((kc * 4 + quad) ^ ml) * 8;
        short8 af = *(const short8*)(As + (w * 16 + ml) * 128 + gl);
#pragma unroll
        for (int nt = 0; nt < 8; ++nt) {
            short8 bf = *(const short8*)(Bs + (nt * 16 + ml) * 128 + gl);
            acc[nt] = __builtin_amdgcn_mfma_f32_16x16x32_bf16(af, bf, acc[nt], 0, 0, 0);
        }
    }
    __syncthreads();                  // all waves done reading As/Bs
    unsigned short* Ct = Bs;          // stride 136 shorts (272B, 16B-aligned)
    int lrow = w * 16 + quad * 4;
#pragma unroll
    for (int r = 0; r < 4; ++r)
#pragma unroll
        for (int nt = 0; nt < 8; ++nt)
            Ct[(lrow + r) * 136 + nt * 16 + ml] = f2bf(acc[nt][r]);
    __syncthreads();
#pragma unroll
    for (int m = 0; m < 4; ++m) {
        int i = m * 256 + tid;        // 0..1023
        int r2 = i >> 4, g = i & 15;
        int rg = row0 + r2;
        uint4 v = *(const uint4*)(Ct + r2 * 136 + g * 8);
        if (rg < M)
            *(uint4*)(Whb + (size_t)rg * 128 + g * 8) = v;
    }
}

// ---------------------------------------------------------------------------
// scatter: pos = PR[dst].y + eslot[e].   [round-2 verbatim]
// ---------------------------------------------------------------------------
__global__ __launch_bounds__(256) void scatter_kernel(const int* __restrict__ ei,
                                                      const float* __restrict__ ef,
                                                      const float* __restrict__ s1,
                                                      const uint2* __restrict__ PR,
                                                      const int* __restrict__ eslot,
                                                      uint2* __restrict__ rec8, int E) {
    int e = blockIdx.x * blockDim.x + threadIdx.x;
    if (e >= E) return;
    int src = ei[e];
    int dst = ei[E + e];
    uint2 pr = PR[dst];
    float s = s1[src] + __uint_as_float(pr.x);
    s = (s >= 0.f) ? s : ALPHA * s;
    unsigned short b0 = f2bf(__expf(s * ef[e * 3 + 0]));
    unsigned short b1 = f2bf(__expf(s * ef[e * 3 + 1]));
    unsigned short b2 = f2bf(__expf(s * ef[e * 3 + 2]));
    uint2 rv;
    rv.x = (uint32)src | ((uint32)(b0 & 0x7fffu) << 17);
    rv.y = (uint32)(b1 & 0x7fffu) | ((uint32)(b2 & 0x7fffu) << 15);
    int pos = (int)pr.y + eslot[e];
    rec8[pos] = rv;
}

// ---------------------------------------------------------------------------
// agg_fused v3: block = 1024 thr = 16 waves, 16 nodes — EDGE-balanced.
// The block's contiguous edge range [rowptr[nb], rowptr[nb+16]) is split into
// 16 equal contiguous chunks (one per wave, ±1 edge — kills the max-degree
// barrier imbalance that sank rounds 4/5). Each wave accumulates z/d in
// REGISTERS while its CSR row is unchanged (round-2's proven pipelined body)
// and flushes via LDS float atomicAdd on row boundaries (~2 flushes/chunk).
// Then: balanced barrier -> normalize -> round-5's verified phase-B GEMM
// [16x384]@[384x128] from L2-hot WoutT -> out. No z HBM round-trip, no k5.
// ---------------------------------------------------------------------------
__global__ __launch_bounds__(1024) void agg_fused(const uint2* __restrict__ rec8,
                                                  const int* __restrict__ rowptr,
                                                  const uint32* __restrict__ Yu,
                                                  const unsigned short* __restrict__ WoutT,
                                                  float* __restrict__ out, int N) {
    __shared__ float zf[16][390];      // f32 accum: [k*128+ch], d at 384..386 (24.4KB)
    __shared__ uint32 zs32[16 * 192];  // bf16 z tile for phase B (12KB)
    __shared__ int rp[17];
    const int tid  = threadIdx.x;
    const int lane = tid & 63, w = tid >> 6;   // w = 0..15
    const int ml   = lane & 15, quad = lane >> 4;
    const int nb   = blockIdx.x * 16;

    for (int i = tid; i < 16 * 390; i += 1024) (&zf[0][0])[i] = 0.f;
    if (tid < 17) rp[tid] = rowptr[min(nb + tid, N)];
    __syncthreads();

    const int beg = rp[0], end = rp[16];
    const int chunk = (end - beg + 15) >> 4;
    int j    = beg + w * chunk;
    int jEnd = min(j + chunk, end);

    if (j < jEnd) {
        int r = 0;
        while (r < 15 && rp[r + 1] <= j) ++r;
        float z0l = 0.f, z0h = 0.f, z1l = 0.f, z1h = 0.f, z2l = 0.f, z2h = 0.f;
        float dd0 = 0.f, dd1 = 0.f, dd2 = 0.f;

#define FLUSH_ROW()                                                         \
        do {                                                                \
            atomicAdd(&zf[r][lane * 2],       z0l);                         \
            atomicAdd(&zf[r][lane * 2 + 1],   z0h);                         \
            atomicAdd(&zf[r][128 + lane * 2], z1l);                         \
            atomicAdd(&zf[r][129 + lane * 2], z1h);                         \
            atomicAdd(&zf[r][256 + lane * 2], z2l);                         \
            atomicAdd(&zf[r][257 + lane * 2], z2h);                         \
            if (lane == 0) {                                                \
                atomicAdd(&zf[r][384], dd0);                                \
                atomicAdd(&zf[r][385], dd1);                                \
                atomicAdd(&zf[r][386], dd2);                                \
            }                                                               \
            z0l = z0h = z1l = z1h = z2l = z2h = 0.f;                        \
            dd0 = dd1 = dd2 = 0.f;                                          \
        } while (0)

#define EDGE_BODY(SX, SY, U)                                                \
        do {                                                                \
            float w0 = __uint_as_float(((SX) >> 1) & 0x7fff0000u);          \
            float w1 = __uint_as_float(((SY) << 16) & 0x7fff0000u);         \
            float w2 = __uint_as_float(((SY) << 1) & 0x7fff0000u);          \
            dd0 += w0; dd1 += w1; dd2 += w2;                                \
            float yl = bflo(U), yh = bfhi(U);                               \
            z0l += w0 * yl; z0h += w0 * yh;                                 \
            z1l += w1 * yl; z1h += w1 * yh;                                 \
            z2l += w2 * yl; z2h += w2 * yh;                                 \
        } while (0)

        for (; j + 7 < jEnd; j += 8) {
            uint2 rr[8];
#pragma unroll
            for (int q = 0; q < 8; ++q) rr[q] = rec8[j + q];
            uint32 sx[8], sy[8];
#pragma unroll
            for (int q = 0; q < 8; ++q) {
                sx[q] = __builtin_amdgcn_readfirstlane(rr[q].x);
                sy[q] = __builtin_amdgcn_readfirstlane(rr[q].y);
            }
            uint32 u[8];
#pragma unroll
            for (int q = 0; q < 8; ++q)
                u[q] = Yu[(size_t)(sx[q] & 0x1ffffu) * 64 + lane];
#pragma unroll
            for (int q = 0; q < 8; ++q) {
                while (j + q >= rp[r + 1]) { FLUSH_ROW(); ++r; }
                EDGE_BODY(sx[q], sy[q], u[q]);
            }
        }
        for (; j < jEnd; ++j) {
            uint2 rr = rec8[j];
            uint32 sx = __builtin_amdgcn_readfirstlane(rr.x);
            uint32 sy = __builtin_amdgcn_readfirstlane(rr.y);
            uint32 u0 = Yu[(size_t)(sx & 0x1ffffu) * 64 + lane];
            while (j >= rp[r + 1]) { FLUSH_ROW(); ++r; }
            EDGE_BODY(sx, sy, u0);
        }
        FLUSH_ROW();
#undef FLUSH_ROW
#undef EDGE_BODY
    }
    __syncthreads();

    // normalize row w -> bf16 zs (XOR-swizzled, round-5 layout)
    {
        float i0 = 1.f / (zf[w][384] + 1e-16f);
        float i1 = 1.f / (zf[w][385] + 1e-16f);
        float i2 = 1.f / (zf[w][386] + 1e-16f);
        uint32 zp[3] = { pk2bf(zf[w][lane * 2] * i0,       zf[w][lane * 2 + 1] * i0),
                         pk2bf(zf[w][128 + lane * 2] * i1, zf[w][129 + lane * 2] * i1),
                         pk2bf(zf[w][256 + lane * 2] * i2, zf[w][257 + lane * 2] * i2) };
#pragma unroll
        for (int k = 0; k < 3; ++k) {
            int g  = k * 16 + (lane >> 2);
            int sg = (g & ~7) | ((g ^ w) & 7);
            zs32[w * 192 + sg * 4 + (lane & 3)] = zp[k];
        }
    }
    __syncthreads();

    // Phase B (round-5 verbatim): wave w -> col-tile (w&7), k-half (w>>3)
    const int n0 = (w & 7) * 16;
    const int kh = w >> 3;
    f32x4 acc = (f32x4){0.f, 0.f, 0.f, 0.f};
    const unsigned short* zs16 = (const unsigned short*)zs32;
#pragma unroll
    for (int ks = 0; ks < 6; ++ks) {
        int g  = kh * 24 + ks * 4 + quad;
        int sg = (g & ~7) | ((g ^ ml) & 7);
        short8 af = *(const short8*)(zs16 + ml * 384 + sg * 8);
        short8 bf = *(const short8*)(WoutT + (size_t)(n0 + ml) * 384 + g * 8);
        acc = __builtin_amdgcn_mfma_f32_16x16x32_bf16(af, bf, acc, 0, 0, 0);
    }
    __syncthreads();                       // zs reads done -> reuse zf as Ct
    float* CtS = &zf[0][0];                // 2 * 16 * 132 floats = 16.9KB (< zf)
#pragma unroll
    for (int r = 0; r < 4; ++r)
        CtS[kh * 2112 + (quad * 4 + r) * 132 + n0 + ml] = acc[r];
    __syncthreads();
    if (tid < 512) {
        int row = tid >> 5, g = tid & 31;  // 16 rows x 32 float4
        int nd  = nb + row;
        if (nd < N) {
            float4 a = *(const float4*)(CtS + row * 132 + g * 4);
            float4 b = *(const float4*)(CtS + 2112 + row * 132 + g * 4);
            *(float4*)(out + (size_t)nd * 128 + g * 4) =
                make_float4(a.x + b.x, a.y + b.y, a.z + b.z, a.w + b.w);
        }
    }
}

// ---------------------------------------------------------------------------
extern "C" void kernel_launch(void* const* d_in, const int* in_sizes, int n_in,
                              void* d_out, int out_size, void* d_ws, size_t ws_size,
                              hipStream_t stream) {
    const float* h    = (const float*)d_in[0];
    const int*   ei   = (const int*)d_in[1];    // [2, E]
    const float* ef   = (const float*)d_in[2];  // [E, 3]
    const float* W    = (const float*)d_in[3];  // [128,128]
    const float* a1   = (const float*)d_in[4];  // [128]
    const float* a2   = (const float*)d_in[5];  // [128]
    const float* Wout = (const float*)d_in[6];  // [384,128]
    float*       out  = (float*)d_out;

    const int N = in_sizes[0] / 128;  // 50000
    const int E = in_sizes[2] / 3;    // 800000
    const int nchunk = (N + 1023) / 1024;
    const int nbh    = (E + 255) / 256;   // hist blocks
    const int nbm    = (N + 63) / 64;     // mmy blocks

    // workspace layout (rec8 first -> 16B alignment for everything vectorized)
    uint2* rec8 = (uint2*)d_ws;                           // E * 8B
    unsigned short* Whb = (unsigned short*)(rec8 + E);    // N*128 bf16 (12.8MB)
    unsigned short* WBT = Whb + (size_t)N * 128;          // 128*128 bf16
    unsigned short* WoutT = WBT + 128 * 128;              // 128*384 bf16
    float* w1f  = (float*)(WoutT + 128 * 384);            // 128
    float* w2f  = w1f + 128;                              // 128
    float* s1   = w2f + 128;                              // N
    uint2* PR   = (uint2*)(s1 + N);                       // N pairs {s2, rowptr}
    int* rowptr = (int*)(PR + N);                         // N+4 (16B-align pad)
    int* counts = rowptr + N + 4;                         // N
    int* eslot  = counts + N;                             // E

    (void)hipMemsetAsync(counts, 0, (size_t)N * sizeof(int), stream);

    k1_hist_prep<<<nbh + 25, 256, 0, stream>>>(ei, counts, eslot, E,
                                               W, Wout, a1, a2, WBT, WoutT, w1f, w2f, nbh);
    k2_mmy_scan<<<nbm + nchunk, 256, 0, stream>>>(h, WBT, w1f, w2f, Whb, s1, PR, N,
                                                  counts, rowptr, N, E, nbm);
    scatter_kernel<<<(E + 255) / 256, 256, 0, stream>>>(ei, ef, s1, PR, eslot, rec8, E);
    agg_fused<<<(N + 15) / 16, 1024, 0, stream>>>(rec8, rowptr, (const uint32*)Whb,
                                                  WoutT, out, N);
}

// Round 7
// 212.095 us; speedup vs baseline: 1.9103x; 1.9103x over previous
//
#include <hip/hip_runtime.h>
#include <hip/hip_bf16.h>

#define ALPHA 0.2f
typedef unsigned int uint32;
typedef __attribute__((ext_vector_type(8))) short short8;   // 8 bf16 = 4 VGPRs
typedef __attribute__((ext_vector_type(4))) float f32x4;

static __device__ __forceinline__ unsigned short f2bf(float f) {
    unsigned int u = __float_as_uint(f);
    u += 0x7fffu + ((u >> 16) & 1u);          // RNE
    return (unsigned short)(u >> 16);
}
static __device__ __forceinline__ uint32 pk2bf(float lo, float hi) {
    return (uint32)f2bf(lo) | ((uint32)f2bf(hi) << 16);
}
static __device__ __forceinline__ float bflo(uint32 u) { return __uint_as_float(u << 16); }
static __device__ __forceinline__ float bfhi(uint32 u) { return __uint_as_float(u & 0xffff0000u); }

// ---------------------------------------------------------------------------
// K1 = hist (blocks 0..nbh-1) ∥ prep (blocks nbh..nbh+24).
// hist: eslot[e] = counts[dst]++ (atomic-return over 800k independent threads,
//       2 edges/thread vectorized. Round-3 proved cursor atomics in scatter
//       serialize on dst contention: 108µs. Round-6 proved LDS-CAS flush
//       serializes too. This split is the proven shape.)
// prep: transpose-cast W -> WBT, Wout -> WoutT (bf16 [n][c]); w1f/w2f = W@a.
// ---------------------------------------------------------------------------
__global__ __launch_bounds__(256) void k1_hist_prep(const int* __restrict__ ei,
                                                    int* __restrict__ counts,
                                                    int* __restrict__ eslot, int E,
                                                    const float* __restrict__ W,
                                                    const float* __restrict__ Wout,
                                                    const float* __restrict__ a1,
                                                    const float* __restrict__ a2,
                                                    unsigned short* __restrict__ WBT,
                                                    unsigned short* __restrict__ WoutT,
                                                    float* __restrict__ w1f,
                                                    float* __restrict__ w2f, int nbh) {
    const int tid = threadIdx.x;
    if ((int)blockIdx.x < nbh) {
        int e0 = (blockIdx.x * 256 + tid) * 2;
        if (e0 + 1 < E) {
            int2 d = *(const int2*)(ei + E + e0);
            eslot[e0]     = atomicAdd(&counts[d.x], 1);
            eslot[e0 + 1] = atomicAdd(&counts[d.y], 1);
        } else if (e0 < E) {
            eslot[e0] = atomicAdd(&counts[ei[E + e0]], 1);
        }
        return;
    }
    int bp = blockIdx.x - nbh;
    if (bp < 8) {
        // WBT[n][c] = bf16(W[c][n]) — 16 n-rows per block
        for (int n = bp * 16; n < bp * 16 + 16; ++n)
            for (int c = tid; c < 128; c += 256)
                WBT[n * 128 + c] = f2bf(W[c * 128 + n]);
    } else if (bp < 24) {
        // WoutT[n][c] = bf16(Wout[c][n]), c=0..383 — 8 n-rows per block
        int q = bp - 8;
        for (int n = q * 8; n < q * 8 + 8; ++n)
            for (int c = tid; c < 384; c += 256)
                WoutT[n * 384 + c] = f2bf(Wout[c * 128 + n]);
    } else {
        if (tid < 128) {
            float acc1 = 0.f, acc2 = 0.f;
            for (int c = 0; c < 128; ++c) {
                float w = W[tid * 128 + c];
                acc1 += w * a1[c];
                acc2 += w * a2[c];
            }
            w1f[tid] = acc1;
            w2f[tid] = acc2;
        }
    }
}

// ---------------------------------------------------------------------------
// K2 = mmy (blocks 0..nbm-1) ∥ scan (blocks nbm..).   [round-2 verbatim]
// mmy: 64-row tiles, 16x16x32 bf16 MFMA, Whb = h@W, s1/s2 fused in A-staging.
//   s2 -> PR[n].x; scan -> PR[n].y = rowptr + pristine rowptr[] for agg.
// ---------------------------------------------------------------------------
__global__ __launch_bounds__(256) void k2_mmy_scan(const float* __restrict__ h,
                                                   const unsigned short* __restrict__ WBT,
                                                   const float* __restrict__ w1f,
                                                   const float* __restrict__ w2f,
                                                   unsigned short* __restrict__ Whb,
                                                   float* __restrict__ s1,
                                                   uint2* __restrict__ PR, int M,
                                                   const int* __restrict__ counts,
                                                   int* __restrict__ rowptr,
                                                   int N, int E, int nbm) {
    __shared__ unsigned short As[64 * 128];   // 16KB
    __shared__ unsigned short Bs[128 * 128];  // 32KB (also epilogue transpose buf)
    __shared__ float ws1[128], ws2[128];
    __shared__ int wsums[4];
    __shared__ int base_s;
    const int tid = threadIdx.x;

    if ((int)blockIdx.x >= nbm) {
        // ---------------- scan ----------------
        const int bs   = blockIdx.x - nbm;
        const int lane = tid & 63, wv = tid >> 6;
        const int limit = bs * 1024;
        int acc = 0;
        for (int i = tid * 4; i < limit; i += 1024) {
            int4 v = *(const int4*)(counts + i);
            acc += v.x + v.y + v.z + v.w;
        }
#pragma unroll
        for (int off = 32; off > 0; off >>= 1) acc += __shfl_down(acc, off);
        if (lane == 0) wsums[wv] = acc;
        __syncthreads();
        if (tid == 0) base_s = wsums[0] + wsums[1] + wsums[2] + wsums[3];
        __syncthreads();
        int i0 = bs * 1024 + tid * 4;
        int v0 = 0, v1 = 0, v2 = 0, v3 = 0;
        if (i0 + 3 < N) {
            int4 v = *(const int4*)(counts + i0);
            v0 = v.x; v1 = v.y; v2 = v.z; v3 = v.w;
        } else {
            if (i0 + 0 < N) v0 = counts[i0 + 0];
            if (i0 + 1 < N) v1 = counts[i0 + 1];
            if (i0 + 2 < N) v2 = counts[i0 + 2];
            if (i0 + 3 < N) v3 = counts[i0 + 3];
        }
        int tt = v0 + v1 + v2 + v3;
        int incl = tt;
#pragma unroll
        for (int off = 1; off < 64; off <<= 1) {
            int t = __shfl_up(incl, off);
            if (lane >= off) incl += t;
        }
        __syncthreads();
        if (lane == 63) wsums[wv] = incl;
        __syncthreads();
        int woff = 0;
        for (int w2 = 0; w2 < wv; ++w2) woff += wsums[w2];
        int base = base_s + woff + (incl - tt);
        if (i0 + 0 < N) { rowptr[i0 + 0] = base;                PR[i0 + 0].y = (uint32)base; }
        if (i0 + 1 < N) { rowptr[i0 + 1] = base + v0;           PR[i0 + 1].y = (uint32)(base + v0); }
        if (i0 + 2 < N) { rowptr[i0 + 2] = base + v0 + v1;      PR[i0 + 2].y = (uint32)(base + v0 + v1); }
        if (i0 + 3 < N) { rowptr[i0 + 3] = base + v0 + v1 + v2; PR[i0 + 3].y = (uint32)(base + v0 + v1 + v2); }
        if (bs == 0 && tid == 0) rowptr[N] = E;
        return;
    }

    // ---------------- mmy (64-row tile) ----------------
    const int lane = tid & 63;
    const int w    = tid >> 6;
    const int row0 = blockIdx.x * 64;

    if (tid < 128) ws1[tid] = w1f[tid];
    else           ws2[tid - 128] = w2f[tid - 128];
    __syncthreads();

    // stage A (fp32 -> bf16) + fused fp32 score partials
    const float4* h4 = (const float4*)h;
    float sp1[4], sp2[4];
#pragma unroll
    for (int m = 0; m < 4; ++m) { sp1[m] = 0.f; sp2[m] = 0.f; }
#pragma unroll
    for (int m = 0; m < 4; ++m) {
        int i = m * 256 + tid;            // 0..1023
        int r = i >> 4, g = i & 15;
        int rg = row0 + r;
        float4 va = make_float4(0.f, 0.f, 0.f, 0.f), vb = va;
        if (rg < M) {
            va = h4[(size_t)rg * 32 + g * 2];
            vb = h4[(size_t)rg * 32 + g * 2 + 1];
        }
        float4 wa1 = *(const float4*)(ws1 + g * 8);
        float4 wb1 = *(const float4*)(ws1 + g * 8 + 4);
        float4 wa2 = *(const float4*)(ws2 + g * 8);
        float4 wb2 = *(const float4*)(ws2 + g * 8 + 4);
        sp1[m] += va.x * wa1.x + va.y * wa1.y + va.z * wa1.z + va.w * wa1.w
                + vb.x * wb1.x + vb.y * wb1.y + vb.z * wb1.z + vb.w * wb1.w;
        sp2[m] += va.x * wa2.x + va.y * wa2.y + va.z * wa2.z + va.w * wa2.w
                + vb.x * wb2.x + vb.y * wb2.y + vb.z * wb2.z + vb.w * wb2.w;
        uint4 u;
        u.x = pk2bf(va.x, va.y); u.y = pk2bf(va.z, va.w);
        u.z = pk2bf(vb.x, vb.y); u.w = pk2bf(vb.z, vb.w);
        *(uint4*)(As + r * 128 + ((g ^ (r & 15)) * 8)) = u;
    }
#pragma unroll
    for (int m = 0; m < 4; ++m) {
#pragma unroll
        for (int off = 1; off < 16; off <<= 1) {
            sp1[m] += __shfl_xor(sp1[m], off);
            sp2[m] += __shfl_xor(sp2[m], off);
        }
    }
    if ((tid & 15) == 0) {
#pragma unroll
        for (int m = 0; m < 4; ++m) {
            int rg = row0 + m * 16 + (tid >> 4);
            if (rg < M) { s1[rg] = sp1[m]; PR[rg].x = __float_as_uint(sp2[m]); }
        }
    }

    // stage B = WBT (128 n-rows, 128 k)
#pragma unroll
    for (int m = 0; m < 8; ++m) {
        int i = m * 256 + tid;
        int n = i >> 4, g = i & 15;
        uint4 v = *(const uint4*)(WBT + n * 128 + g * 8);
        *(uint4*)(Bs + n * 128 + ((g ^ (n & 15)) * 8)) = v;
    }
    __syncthreads();

    const int ml   = lane & 15;
    const int quad = lane >> 4;
    f32x4 acc[8];
#pragma unroll
    for (int nt = 0; nt < 8; ++nt) acc[nt] = (f32x4){0.f, 0.f, 0.f, 0.f};
#pragma unroll
    for (int kc = 0; kc < 4; ++kc) {
        int gl = ((kc * 4 + quad) ^ ml) * 8;
        short8 af = *(const short8*)(As + (w * 16 + ml) * 128 + gl);
#pragma unroll
        for (int nt = 0; nt < 8; ++nt) {
            short8 bf = *(const short8*)(Bs + (nt * 16 + ml) * 128 + gl);
            acc[nt] = __builtin_amdgcn_mfma_f32_16x16x32_bf16(af, bf, acc[nt], 0, 0, 0);
        }
    }
    // epilogue: acc -> Ct (=Bs, free now) -> coalesced uint4 stores of Whb
    __syncthreads();                  // all waves done reading As/Bs
    unsigned short* Ct = Bs;          // stride 136 shorts (272B, 16B-aligned)
    int lrow = w * 16 + quad * 4;
#pragma unroll
    for (int r = 0; r < 4; ++r)
#pragma unroll
        for (int nt = 0; nt < 8; ++nt)
            Ct[(lrow + r) * 136 + nt * 16 + ml] = f2bf(acc[nt][r]);
    __syncthreads();
#pragma unroll
    for (int m = 0; m < 4; ++m) {
        int i = m * 256 + tid;        // 0..1023
        int r2 = i >> 4, g = i & 15;
        int rg = row0 + r2;
        uint4 v = *(const uint4*)(Ct + r2 * 136 + g * 8);
        if (rg < M)
            *(uint4*)(Whb + (size_t)rg * 128 + g * 8) = v;
    }
}

// ---------------------------------------------------------------------------
// scatter: 2 edges/thread, vectorized int2/float2 streams. pos = PR[dst].y +
// eslot[e]; write 8B record {src:17b | ex0:15b, ex1:15b | ex2:15b<<15}.
// PR[dst] is ONE random 8B gather for both s2 and rowptr.
// ---------------------------------------------------------------------------
__global__ __launch_bounds__(256) void scatter_kernel(const int* __restrict__ ei,
                                                      const float* __restrict__ ef,
                                                      const float* __restrict__ s1,
                                                      const uint2* __restrict__ PR,
                                                      const int* __restrict__ eslot,
                                                      uint2* __restrict__ rec8, int E) {
    int e0 = (blockIdx.x * blockDim.x + threadIdx.x) * 2;
    if (e0 >= E) return;
    if (e0 + 1 < E) {
        int2 sv = *(const int2*)(ei + e0);
        int2 dv = *(const int2*)(ei + E + e0);
        int2 es = *(const int2*)(eslot + e0);
        float2 f01 = *(const float2*)(ef + (size_t)e0 * 3);
        float2 f23 = *(const float2*)(ef + (size_t)e0 * 3 + 2);
        float2 f45 = *(const float2*)(ef + (size_t)e0 * 3 + 4);
        float sa = s1[sv.x];
        float sb = s1[sv.y];
        uint2 pa = PR[dv.x];
        uint2 pb = PR[dv.y];
        float s_a = sa + __uint_as_float(pa.x);
        float s_b = sb + __uint_as_float(pb.x);
        s_a = (s_a >= 0.f) ? s_a : ALPHA * s_a;
        s_b = (s_b >= 0.f) ? s_b : ALPHA * s_b;
        unsigned short a0 = f2bf(__expf(s_a * f01.x));
        unsigned short a1 = f2bf(__expf(s_a * f01.y));
        unsigned short a2 = f2bf(__expf(s_a * f23.x));
        unsigned short b0 = f2bf(__expf(s_b * f23.y));
        unsigned short b1 = f2bf(__expf(s_b * f45.x));
        unsigned short b2 = f2bf(__expf(s_b * f45.y));
        uint2 rva, rvb;
        rva.x = (uint32)sv.x | ((uint32)(a0 & 0x7fffu) << 17);
        rva.y = (uint32)(a1 & 0x7fffu) | ((uint32)(a2 & 0x7fffu) << 15);
        rvb.x = (uint32)sv.y | ((uint32)(b0 & 0x7fffu) << 17);
        rvb.y = (uint32)(b1 & 0x7fffu) | ((uint32)(b2 & 0x7fffu) << 15);
        rec8[(int)pa.y + es.x] = rva;
        rec8[(int)pb.y + es.y] = rvb;
    } else {
        int src = ei[e0];
        int dst = ei[E + e0];
        uint2 pr = PR[dst];
        float s = s1[src] + __uint_as_float(pr.x);
        s = (s >= 0.f) ? s : ALPHA * s;
        unsigned short b0 = f2bf(__expf(s * ef[(size_t)e0 * 3 + 0]));
        unsigned short b1 = f2bf(__expf(s * ef[(size_t)e0 * 3 + 1]));
        unsigned short b2 = f2bf(__expf(s * ef[(size_t)e0 * 3 + 2]));
        uint2 rv;
        rv.x = (uint32)src | ((uint32)(b0 & 0x7fffu) << 17);
        rv.y = (uint32)(b1 & 0x7fffu) | ((uint32)(b2 & 0x7fffu) << 15);
        rec8[(int)pr.y + eslot[e0]] = rv;
    }
}

// ---------------------------------------------------------------------------
// agg: one wave per node, atomic-free, one pass, SCALARIZED. rec8 records and
// rowptr bounds are wave-uniform: readfirstlane the INDEX so the compiler
// proves uniformity and emits s_load (scalar cache) for them — the vector
// memory pipe is reserved for the truly divergent Yu gathers. Weight decode
// on SALU; FMAs take SGPR weight directly. x8 main loop for load MLP.
// [round-3/6 lessons: no cursor atomics, no LDS flush, no inter-wave barrier]
// ---------------------------------------------------------------------------
__global__ __launch_bounds__(256) void agg_kernel(const uint2* __restrict__ rec8,
                                                  const int* __restrict__ rowptr,
                                                  const uint32* __restrict__ Yu,
                                                  uint32* __restrict__ zo, int N) {
    int node = (blockIdx.x * blockDim.x + threadIdx.x) >> 6;
    int lane = threadIdx.x & 63;
    if (node >= N) return;
    int nu  = __builtin_amdgcn_readfirstlane(node);
    int beg = rowptr[nu], end = rowptr[nu + 1];

    float d0 = 0.f, d1 = 0.f, d2 = 0.f;
    float z0l = 0.f, z0h = 0.f, z1l = 0.f, z1h = 0.f, z2l = 0.f, z2h = 0.f;
    int j = beg;

    for (; j + 7 < end; j += 8) {
        const uint2* rb = rec8 + (unsigned)__builtin_amdgcn_readfirstlane(j);
        uint2 rr[8];
#pragma unroll
        for (int q = 0; q < 8; ++q) rr[q] = rb[q];
        uint32 sx[8], sy[8];
#pragma unroll
        for (int q = 0; q < 8; ++q) {
            sx[q] = __builtin_amdgcn_readfirstlane(rr[q].x);
            sy[q] = __builtin_amdgcn_readfirstlane(rr[q].y);
        }
        uint32 u[8];
#pragma unroll
        for (int q = 0; q < 8; ++q)
            u[q] = Yu[(size_t)(sx[q] & 0x1ffffu) * 64 + lane];
#pragma unroll
        for (int q = 0; q < 8; ++q) {
            float w0 = __uint_as_float((sx[q] >> 1) & 0x7fff0000u);
            float w1 = __uint_as_float((sy[q] << 16) & 0x7fff0000u);
            float w2 = __uint_as_float((sy[q] << 1) & 0x7fff0000u);
            d0 += w0; d1 += w1; d2 += w2;
            float yl = bflo(u[q]), yh = bfhi(u[q]);
            z0l += w0 * yl; z0h += w0 * yh;
            z1l += w1 * yl; z1h += w1 * yh;
            z2l += w2 * yl; z2h += w2 * yh;
        }
    }
    for (; j + 3 < end; j += 4) {
        const uint2* rb = rec8 + (unsigned)__builtin_amdgcn_readfirstlane(j);
        uint2 rr[4];
#pragma unroll
        for (int q = 0; q < 4; ++q) rr[q] = rb[q];
        uint32 sx[4], sy[4];
#pragma unroll
        for (int q = 0; q < 4; ++q) {
            sx[q] = __builtin_amdgcn_readfirstlane(rr[q].x);
            sy[q] = __builtin_amdgcn_readfirstlane(rr[q].y);
        }
        uint32 u[4];
#pragma unroll
        for (int q = 0; q < 4; ++q)
            u[q] = Yu[(size_t)(sx[q] & 0x1ffffu) * 64 + lane];
#pragma unroll
        for (int q = 0; q < 4; ++q) {
            float w0 = __uint_as_float((sx[q] >> 1) & 0x7fff0000u);
            float w1 = __uint_as_float((sy[q] << 16) & 0x7fff0000u);
            float w2 = __uint_as_float((sy[q] << 1) & 0x7fff0000u);
            d0 += w0; d1 += w1; d2 += w2;
            float yl = bflo(u[q]), yh = bfhi(u[q]);
            z0l += w0 * yl; z0h += w0 * yh;
            z1l += w1 * yl; z1h += w1 * yh;
            z2l += w2 * yl; z2h += w2 * yh;
        }
    }
    for (; j < end; ++j) {
        const uint2* rb = rec8 + (unsigned)__builtin_amdgcn_readfirstlane(j);
        uint2 r0 = rb[0];
        uint32 sx = __builtin_amdgcn_readfirstlane(r0.x);
        uint32 sy = __builtin_amdgcn_readfirstlane(r0.y);
        uint32 u0 = Yu[(size_t)(sx & 0x1ffffu) * 64 + lane];
        float w0 = __uint_as_float((sx >> 1) & 0x7fff0000u);
        float w1 = __uint_as_float((sy << 16) & 0x7fff0000u);
        float w2 = __uint_as_float((sy << 1) & 0x7fff0000u);
        d0 += w0; d1 += w1; d2 += w2;
        float yl = bflo(u0), yh = bfhi(u0);
        z0l += w0 * yl; z0h += w0 * yh;
        z1l += w1 * yl; z1h += w1 * yh;
        z2l += w2 * yl; z2h += w2 * yh;
    }
    float i0 = 1.f / (d0 + 1e-16f);
    float i1 = 1.f / (d1 + 1e-16f);
    float i2 = 1.f / (d2 + 1e-16f);
    size_t zb = (size_t)node * 192;
    zo[zb + lane]       = pk2bf(z0l * i0, z0h * i0);
    zo[zb + 64 + lane]  = pk2bf(z1l * i1, z1h * i1);
    zo[zb + 128 + lane] = pk2bf(z2l * i2, z2h * i2);
}

// ---------------------------------------------------------------------------
// K5: out[N,128] = z[N,384] @ Wout[384,128].   [round-2 verbatim]
// z is L2-warm (agg just wrote it), so the round-trip's HBM cost is mostly
// the 38MB write — fusion attempts (r3/r4/r6) all cost more than this saves.
// ---------------------------------------------------------------------------
__global__ __launch_bounds__(256) void k5_gemm(const unsigned short* __restrict__ z,
                                               const unsigned short* __restrict__ WoutT,
                                               float* __restrict__ out, int M) {
    __shared__ __align__(16) char smem[49152];
    unsigned short* As = (unsigned short*)smem;            // 64*128 bf16 = 16KB
    unsigned short* Bs = (unsigned short*)(smem + 16384);  // 128*128 bf16 = 32KB
    float* Ct = (float*)smem;                              // 64*132 f32 (epilogue)
    const int tid = threadIdx.x;
    const int lane = tid & 63, w = tid >> 6;
    const int ml = lane & 15, quad = lane >> 4;
    const int row0 = blockIdx.x * 64;

    f32x4 acc[8];
#pragma unroll
    for (int nt = 0; nt < 8; ++nt) acc[nt] = (f32x4){0.f, 0.f, 0.f, 0.f};

    for (int ks = 0; ks < 3; ++ks) {
        __syncthreads();              // prev slice compute done
#pragma unroll
        for (int m = 0; m < 4; ++m) { // stage A slice: 64 rows x 128 bf16
            int i = m * 256 + tid;
            int r = i >> 4, g = i & 15;
            int rg = row0 + r;
            uint4 v = make_uint4(0u, 0u, 0u, 0u);
            if (rg < M) v = *(const uint4*)(z + (size_t)rg * 384 + ks * 128 + g * 8);
            *(uint4*)(As + r * 128 + ((g ^ (r & 15)) * 8)) = v;
        }
#pragma unroll
        for (int m = 0; m < 8; ++m) { // stage B slice: 128 n-rows x 128 k
            int i = m * 256 + tid;
            int n = i >> 4, g = i & 15;
            uint4 v = *(const uint4*)(WoutT + n * 384 + ks * 128 + g * 8);
            *(uint4*)(Bs + n * 128 + ((g ^ (n & 15)) * 8)) = v;
        }
        __syncthreads();
#pragma unroll
        for (int kc = 0; kc < 4; ++kc) {
            int gl = ((kc * 4 + quad) ^ ml) * 8;
            short8 af = *(const short8*)(As + (w * 16 + ml) * 128 + gl);
#pragma unroll
            for (int nt = 0; nt < 8; ++nt) {
                short8 bf = *(const short8*)(Bs + (nt * 16 + ml) * 128 + gl);
                acc[nt] = __builtin_amdgcn_mfma_f32_16x16x32_bf16(af, bf, acc[nt], 0, 0, 0);
            }
        }
    }
    __syncthreads();
    int lrow = w * 16 + quad * 4;
#pragma unroll
    for (int r = 0; r < 4; ++r)
#pragma unroll
        for (int nt = 0; nt < 8; ++nt)
            Ct[(lrow + r) * 132 + nt * 16 + ml] = acc[nt][r];
    __syncthreads();
#pragma unroll
    for (int m = 0; m < 8; ++m) {
        int i = m * 256 + tid;
        int r2 = i >> 5, g = i & 31;
        int rg = row0 + r2;
        if (rg < M)
            *(float4*)(out + (size_t)rg * 128 + g * 4) = *(const float4*)(Ct + r2 * 132 + g * 4);
    }
}

// ---------------------------------------------------------------------------
extern "C" void kernel_launch(void* const* d_in, const int* in_sizes, int n_in,
                              void* d_out, int out_size, void* d_ws, size_t ws_size,
                              hipStream_t stream) {
    const float* h    = (const float*)d_in[0];
    const int*   ei   = (const int*)d_in[1];    // [2, E]
    const float* ef   = (const float*)d_in[2];  // [E, 3]
    const float* W    = (const float*)d_in[3];  // [128,128]
    const float* a1   = (const float*)d_in[4];  // [128]
    const float* a2   = (const float*)d_in[5];  // [128]
    const float* Wout = (const float*)d_in[6];  // [384,128]
    float*       out  = (float*)d_out;

    const int N = in_sizes[0] / 128;  // 50000
    const int E = in_sizes[2] / 3;    // 800000
    const int nchunk = (N + 1023) / 1024;
    const int nbh    = (E + 511) / 512;   // hist blocks (2 edges/thread)
    const int nbm    = (N + 63) / 64;     // mmy blocks

    // workspace layout (rec8 first -> 16B alignment for everything vectorized)
    uint2* rec8 = (uint2*)d_ws;                           // E * 8B
    unsigned short* Whb = (unsigned short*)(rec8 + E);    // N*128 bf16 (12.8MB)
    unsigned short* WBT = Whb + (size_t)N * 128;          // 128*128 bf16
    unsigned short* WoutT = WBT + 128 * 128;              // 128*384 bf16
    float* w1f  = (float*)(WoutT + 128 * 384);            // 128
    float* w2f  = w1f + 128;                              // 128
    float* s1   = w2f + 128;                              // N
    uint2* PR   = (uint2*)(s1 + N);                       // N pairs {s2, rowptr}
    int* rowptr = (int*)(PR + N);                         // N+4 (16B-align pad)
    unsigned short* zbuf = (unsigned short*)(rowptr + N + 4);  // N*384 bf16 (38.4MB)
    // counts/eslot alias zbuf: dead before agg writes z (stream order)
    int* counts = (int*)zbuf;                             // N
    int* eslot  = counts + N;                             // E

    (void)hipMemsetAsync(counts, 0, (size_t)N * sizeof(int), stream);

    k1_hist_prep<<<nbh + 25, 256, 0, stream>>>(ei, counts, eslot, E,
                                               W, Wout, a1, a2, WBT, WoutT, w1f, w2f, nbh);
    k2_mmy_scan<<<nbm + nchunk, 256, 0, stream>>>(h, WBT, w1f, w2f, Whb, s1, PR, N,
                                                  counts, rowptr, N, E, nbm);
    scatter_kernel<<<(E / 2 + 255) / 256, 256, 0, stream>>>(ei, ef, s1, PR, eslot, rec8, E);
    agg_kernel<<<(N * 64 + 255) / 256, 256, 0, stream>>>(rec8, rowptr, (const uint32*)Whb,
                                                         (uint32*)zbuf, N);
    k5_gemm<<<(N + 63) / 64, 256, 0, stream>>>(zbuf, WoutT, out, N);
}